// Round 1
// baseline (305.670 us; speedup 1.0000x reference)
//
#include <hip/hip_runtime.h>

#define Lq 512
#define Bn 1024
#define Tq 48

__device__ __forceinline__ float lane_bcast(float v, int lane) {
    return __uint_as_float(__builtin_amdgcn_readlane(__float_as_uint(v), lane));
}

// ---------------- Forward algorithm (log partition function) ----------------
// One wave (64 threads) per batch element. Lane j holds P[j] (linear-domain
// forward prob) and register column w[i] = exp(trans[i][j]). Per step:
//   s[j] = sum_i P[i]*w[i][j]   (48 readlane-broadcast FMAs)
//   P[j] = s[j] * exp(e_t[j])
// Rescale by wave-max every 4 steps; accumulate log of scales in c2.
__global__ __launch_bounds__(64) void crf_forward(
    const float* __restrict__ em, const int* __restrict__ mask,
    const float* __restrict__ startT, const float* __restrict__ endT,
    const float* __restrict__ trans, float* __restrict__ out)
{
    const int b = blockIdx.x;
    const int j = threadIdx.x;
    const int jc = j < Tq ? j : Tq - 1;   // clamp so inactive lanes load valid addrs
    const bool act = j < Tq;

    // Preload W column j into registers: w[i] = exp(trans[i][j])
    float w[Tq];
#pragma unroll
    for (int i = 0; i < Tq; ++i) {
        float tv = trans[i * Tq + jc];
        w[i] = act ? __expf(tv) : 0.0f;
    }

    // init: P = exp(start + emissions[0])
    float p = act ? __expf(startT[jc] + em[(size_t)b * Tq + jc]) : 0.0f;
    float c2 = 0.0f;  // accumulated log-scale (natural log)

    // software-pipelined prefetch, 4 steps deep
    const int U = 4;
    float eb[U]; int mb[U];
#pragma unroll
    for (int u = 0; u < U; ++u) {
        int t = 1 + u;
        eb[u] = em[((size_t)t * Bn + b) * Tq + jc];
        mb[u] = mask[t * Bn + b];
    }

    for (int t = 1; t < Lq; t += U) {
        float en[U]; int mn[U];
#pragma unroll
        for (int u = 0; u < U; ++u) {
            int tn = t + U + u;
            if (tn < Lq) {
                en[u] = em[((size_t)tn * Bn + b) * Tq + jc];
                mn[u] = mask[tn * Bn + b];
            } else { en[u] = 0.0f; mn[u] = 0; }
        }
#pragma unroll
        for (int u = 0; u < U; ++u) {
            if (mb[u] != 0) {   // wave-uniform branch (all lanes read same mask)
                float a0 = 0.f, a1 = 0.f, a2 = 0.f, a3 = 0.f;
#pragma unroll
                for (int i = 0; i < Tq; i += 4) {
                    a0 = fmaf(lane_bcast(p, i + 0), w[i + 0], a0);
                    a1 = fmaf(lane_bcast(p, i + 1), w[i + 1], a1);
                    a2 = fmaf(lane_bcast(p, i + 2), w[i + 2], a2);
                    a3 = fmaf(lane_bcast(p, i + 3), w[i + 3], a3);
                }
                float s = (a0 + a1) + (a2 + a3);
                p = s * __expf(eb[u]);
            }
        }
        // rescale every U steps (worst-case log growth ~10/step << 88/4 steps)
        float M = p;
#pragma unroll
        for (int off = 32; off >= 1; off >>= 1)
            M = fmaxf(M, __shfl_xor(M, off, 64));
        p = p / M;
        c2 += __logf(M);
#pragma unroll
        for (int u = 0; u < U; ++u) { eb[u] = en[u]; mb[u] = mn[u]; }
    }

    // log_z = log(sum_j P[j]*exp(end[j])) + c2 ; accumulate -log_z
    float ez = act ? __expf(endT[jc]) : 0.0f;
    float z = p * ez;
#pragma unroll
    for (int off = 32; off >= 1; off >>= 1)
        z += __shfl_xor(z, off, 64);
    if (j == 0) atomicAdd(out, -(__logf(z) + c2));
}

// ---------------- Numerator (gold-path score) ----------------
// One thread per (t, b). Handles general contiguous-prefix mask.
__global__ __launch_bounds__(256) void crf_llh(
    const float* __restrict__ em, const int* __restrict__ tags,
    const int* __restrict__ mask, const float* __restrict__ startT,
    const float* __restrict__ endT, const float* __restrict__ trans,
    float* __restrict__ out)
{
    int id = blockIdx.x * blockDim.x + threadIdx.x;  // id = t*Bn + b
    float c = 0.0f;
    if (id < Lq * Bn) {
        int t = id / Bn;
        int b = id - t * Bn;
        int tag = tags[id];
        int m_t = mask[id];
        if (t == 0) c += startT[tag];
        bool is_last;
        if (t < Lq - 1) {
            if (m_t) c += em[(size_t)id * Tq + tag];       // emis_at_tags[:-1]*mask[:-1]
            int tag1 = tags[id + Bn];
            int m1 = mask[id + Bn];
            if (m1) c += trans[tag * Tq + tag1];           // trans_scores * mask[1:]
            is_last = (m_t != 0) && (m1 == 0);
        } else {
            is_last = (m_t != 0);
        }
        if (is_last) {
            c += endT[tag];
            int mL = mask[(Lq - 1) * Bn + b];
            if (mL) c += em[((size_t)(Lq - 1) * Bn + b) * Tq + tag];
        }
    }
    // wave reduce then one atomic per wave
#pragma unroll
    for (int off = 32; off >= 1; off >>= 1)
        c += __shfl_xor(c, off, 64);
    if ((threadIdx.x & 63) == 0) atomicAdd(out, c);
}

extern "C" void kernel_launch(void* const* d_in, const int* in_sizes, int n_in,
                              void* d_out, int out_size, void* d_ws, size_t ws_size,
                              hipStream_t stream) {
    const float* em     = (const float*)d_in[0];
    const int*   tags   = (const int*)d_in[1];
    const int*   mask   = (const int*)d_in[2];
    const float* startT = (const float*)d_in[3];
    const float* endT   = (const float*)d_in[4];
    const float* trans  = (const float*)d_in[5];
    float* out = (float*)d_out;

    hipMemsetAsync(out, 0, sizeof(float), stream);
    crf_llh<<<(Lq * Bn) / 256, 256, 0, stream>>>(em, tags, mask, startT, endT, trans, out);
    crf_forward<<<Bn, 64, 0, stream>>>(em, mask, startT, endT, trans, out);
}

// Round 3
// 160.367 us; speedup vs baseline: 1.9061x; 1.9061x over previous
//
#include <hip/hip_runtime.h>

#define Lq 512
#define Bn 1024
#define Tq 48
#define NP 24   // f32 pairs along the i (source-state) axis

typedef float f32x2 __attribute__((ext_vector_type(2)));

// acc += (bc.lo, bc.hi) * (w.lo, w.hi) elementwise, fp32 exact.
// bc is a wave-uniform SGPR pair (two readlane results).
__device__ __forceinline__ f32x2 pk_fma(unsigned long long bc, f32x2 w, f32x2 acc) {
    asm("v_pk_fma_f32 %0, %1, %2, %0" : "+v"(acc) : "s"(bc), "v"(w));
    return acc;
}

// ---------------- Forward algorithm (log partition function) ----------------
// One wave per batch element (1024 blocks x 64 threads). Lane j holds P[j]
// (fp32, linear domain) and f32-pair column wp[m] = (W[2m][j], W[2m+1][j]).
// Per step: 48 readlane (burst) -> 24 v_pk_fma_f32 -> s -> p = s*exp(e).
// Rescale by wave-max every 8 steps. Result written to ws[b] (no atomics).
__global__ __launch_bounds__(64) void crf_forward(
    const float* __restrict__ em, const int* __restrict__ mask,
    const float* __restrict__ startT, const float* __restrict__ endT,
    const float* __restrict__ trans, float* __restrict__ ws)
{
    const int j  = threadIdx.x;       // 0..63
    const int b  = blockIdx.x;        // wave-uniform (scalar)
    const int jc = j < Tq ? j : Tq - 1;
    const bool act = j < Tq;

    // W column j as fp32 pairs
    f32x2 w2[NP];
#pragma unroll
    for (int m = 0; m < NP; ++m) {
        float w0 = __expf(trans[(2*m)   * Tq + jc]);
        float w1 = __expf(trans[(2*m+1) * Tq + jc]);
        w2[m] = act ? (f32x2){w0, w1} : (f32x2){0.0f, 0.0f};  // zero col keeps p=0 inactive
    }

    float p = act ? __expf(startT[jc] + em[(size_t)b * Tq + jc]) : 0.0f;
    float c2 = 0.0f;   // accumulated ln(scale)

    const int U = 8;
    float eb[U]; int mb[U];
#pragma unroll
    for (int u = 0; u < U; ++u) {
        int t = 1 + u;
        eb[u] = (em + ((size_t)t * Bn + b) * Tq)[jc];   // SGPR base + lane offset
        mb[u] = mask[t * Bn + b];                        // uniform -> s_load
    }

    auto step = [&](float e) {
        // burst all 48 readlanes first (no hazard stalls), pack to SGPR pairs
        unsigned long long bc[NP];
        int pu = __float_as_int(p);
#pragma unroll
        for (int m = 0; m < NP; ++m) {
            unsigned lo = (unsigned)__builtin_amdgcn_readlane(pu, 2*m);
            unsigned hi = (unsigned)__builtin_amdgcn_readlane(pu, 2*m + 1);
            bc[m] = ((unsigned long long)hi << 32) | lo;
        }
        f32x2 a0 = {0.f,0.f}, a1 = {0.f,0.f}, a2 = {0.f,0.f}, a3 = {0.f,0.f};
#pragma unroll
        for (int m = 0; m < NP; m += 4) {
            a0 = pk_fma(bc[m],     w2[m],     a0);
            a1 = pk_fma(bc[m + 1], w2[m + 1], a1);
            a2 = pk_fma(bc[m + 2], w2[m + 2], a2);
            a3 = pk_fma(bc[m + 3], w2[m + 3], a3);
        }
        f32x2 s2 = (a0 + a1) + (a2 + a3);
        float s = s2.x + s2.y;
        p = s * __expf(e);
    };

    for (int g = 0; g < (Lq - 1 + U - 1) / U; ++g) {
        // prefetch next group (8 steps ahead >> HBM latency)
        float en[U]; int mn[U];
        const int tn = 1 + (g + 1) * U;
#pragma unroll
        for (int u = 0; u < U; ++u) {
            int t  = tn + u;
            int tc = t < Lq ? t : Lq - 1;
            en[u] = (em + ((size_t)tc * Bn + b) * Tq)[jc];
            mn[u] = t < Lq ? mask[tc * Bn + b] : 0;
        }

        int allm = __builtin_amdgcn_readfirstlane(
            mb[0] & mb[1] & mb[2] & mb[3] & mb[4] & mb[5] & mb[6] & mb[7]);
        if (allm) {                        // common case: straight-line 8 steps
#pragma unroll
            for (int u = 0; u < U; ++u) step(eb[u]);
        } else {                           // tail: per-step SALU-uniform branch
#pragma unroll
            for (int u = 0; u < U; ++u)
                if (__builtin_amdgcn_readfirstlane(mb[u])) step(eb[u]);
        }

        // rescale every 8 steps (worst-case growth ~e^83 < fp32 max)
        float M = p;
#pragma unroll
        for (int off = 32; off >= 1; off >>= 1)
            M = fmaxf(M, __shfl_xor(M, off, 64));
        p = p / M;
        c2 += __logf(M);

#pragma unroll
        for (int u = 0; u < U; ++u) { eb[u] = en[u]; mb[u] = mn[u]; }
    }

    // log_z = ln(sum_j P[j]*exp(end[j])) + c2 ; write -log_z to ws[b]
    float ez = act ? __expf(endT[jc]) : 0.0f;
    float z = p * ez;
#pragma unroll
    for (int off = 32; off >= 1; off >>= 1)
        z += __shfl_xor(z, off, 64);
    if (j == 0) ws[b] = -(__logf(z) + c2);
}

// ---------------- Numerator + final reduction ----------------
// Grid-stride over (t,b); block 0 additionally sums ws[] (forward results).
// One atomic per block.
__global__ __launch_bounds__(256) void crf_llh(
    const float* __restrict__ em, const int* __restrict__ tags,
    const int* __restrict__ mask, const float* __restrict__ startT,
    const float* __restrict__ endT, const float* __restrict__ trans,
    const float* __restrict__ ws, float* __restrict__ out)
{
    float c = 0.0f;
    if (blockIdx.x == 0) {
        for (int i = threadIdx.x; i < Bn; i += 256) c += ws[i];
    }
    for (int id = blockIdx.x * blockDim.x + threadIdx.x; id < Lq * Bn;
         id += gridDim.x * blockDim.x) {
        int t  = id >> 10;          // / Bn (Bn = 1024)
        int bb = id & (Bn - 1);
        int tag = tags[id];
        int m_t = mask[id];
        if (t == 0) c += startT[tag];
        bool is_last;
        if (t < Lq - 1) {
            if (m_t) c += em[(size_t)id * Tq + tag];     // emis*mask[:-1]
            int tag1 = tags[id + Bn];
            int m1   = mask[id + Bn];
            if (m1) c += trans[tag * Tq + tag1];         // trans*mask[1:]
            is_last = (m_t != 0) && (m1 == 0);
        } else {
            is_last = (m_t != 0);
        }
        if (is_last) {
            c += endT[tag];
            int mL = mask[(Lq - 1) * Bn + bb];
            if (mL) c += em[((size_t)(Lq - 1) * Bn + bb) * Tq + tag];
        }
    }
#pragma unroll
    for (int off = 32; off >= 1; off >>= 1)
        c += __shfl_xor(c, off, 64);
    __shared__ float red[4];
    if ((threadIdx.x & 63) == 0) red[threadIdx.x >> 6] = c;
    __syncthreads();
    if (threadIdx.x == 0)
        atomicAdd(out, red[0] + red[1] + red[2] + red[3]);
}

extern "C" void kernel_launch(void* const* d_in, const int* in_sizes, int n_in,
                              void* d_out, int out_size, void* d_ws, size_t ws_size,
                              hipStream_t stream) {
    const float* em     = (const float*)d_in[0];
    const int*   tags   = (const int*)d_in[1];
    const int*   mask   = (const int*)d_in[2];
    const float* startT = (const float*)d_in[3];
    const float* endT   = (const float*)d_in[4];
    const float* trans  = (const float*)d_in[5];
    float* out = (float*)d_out;
    float* ws  = (float*)d_ws;

    hipMemsetAsync(out, 0, sizeof(float), stream);
    crf_forward<<<Bn, 64, 0, stream>>>(em, mask, startT, endT, trans, ws);
    crf_llh<<<512, 256, 0, stream>>>(em, tags, mask, startT, endT, trans, ws, out);
}